// Round 1
// baseline (757.584 us; speedup 1.0000x reference)
//
#include <hip/hip_runtime.h>

// SimpleGCNConv, N=8192, C=128, fp32.
//   out = D^-1/2 (adj + I) D^-1/2 @ (x @ W^T) + b     (associativity: W applied first)
// Pipeline:
//   A: dinv[i] = (1 + rowsum(adj[i]))^-1/2                (HBM-bound, 256 MiB read)
//   B: t[j][c] = dinv[j] * sum_k x[j][k] W[c][k]          (tiny GEMM, 268 MFLOP)
//   C: part/out[i][c] = sum_j (adj[i][j]+diag) t[j][c]    (17.18 GFLOP, fp32 VALU-bound)
//   D: out = dinv[i]*(part0+part1) + b[c]                 (combine K-split halves)

#define N_ROWS 8192
#define N_C    128
#define BM     64
#define BK     64

// ---------------------------------------------------------------------------
// Kernel A: row degrees -> dinv.  One block per row, 32 KiB contiguous read.
// ---------------------------------------------------------------------------
__global__ __launch_bounds__(256) void k_rowsum(const float* __restrict__ adj,
                                                float* __restrict__ dinv) {
    const int row = blockIdx.x;
    const float4* rp = (const float4*)(adj + (size_t)row * N_ROWS);
    float s = 0.f;
#pragma unroll
    for (int i = 0; i < 8; ++i) {                 // 2048 float4 / 256 thr
        float4 v = rp[threadIdx.x + i * 256];
        s += (v.x + v.y) + (v.z + v.w);
    }
#pragma unroll
    for (int off = 32; off > 0; off >>= 1) s += __shfl_down(s, off, 64);
    __shared__ float red[4];
    const int lane = threadIdx.x & 63, wid = threadIdx.x >> 6;
    if (lane == 0) red[wid] = s;
    __syncthreads();
    if (threadIdx.x == 0) {
        float deg = 1.0f + ((red[0] + red[1]) + (red[2] + red[3]));
        dinv[row] = 1.0f / sqrtf(deg);            // deg >= 1, never inf
    }
}

// ---------------------------------------------------------------------------
// Kernel B: t = dinv .* (x @ W^T).  32 rows/block, W transposed into LDS in
// two k-halves (keeps LDS < 64 KiB).  Per-thread 2x8 micro-tile.
// ---------------------------------------------------------------------------
__global__ __launch_bounds__(256) void k_xw(const float* __restrict__ x,
                                            const float* __restrict__ W,
                                            const float* __restrict__ dinv,
                                            float* __restrict__ t) {
    __shared__ __align__(16) float Wt[64][132];   // [k][c], stride 132: 16B-aligned rows, 4-way write conflict only
    __shared__ __align__(16) float xs[32][128];
    const int tid = threadIdx.x;
    const int j0 = blockIdx.x * 32;

    {   // stage x tile (coalesced float4)
        const int c4 = (tid & 31) * 4;
        const int r0 = tid >> 5;
#pragma unroll
        for (int p = 0; p < 4; ++p)
            *(float4*)&xs[r0 + p * 8][c4] =
                *(const float4*)(x + (size_t)(j0 + r0 + p * 8) * N_C + c4);
    }

    const int tc = tid & 15, tr = tid >> 4;
    const int c0 = tc * 8, r0c = tr * 2;
    float acc[2][8];
#pragma unroll
    for (int i = 0; i < 2; ++i)
#pragma unroll
        for (int j = 0; j < 8; ++j) acc[i][j] = 0.f;

    const int c_lo = (tid & 7) + ((tid >> 7) << 3);   // 0..15
    const int k4   = ((tid >> 3) & 15) * 4;           // 0..60

    for (int kh = 0; kh < 2; ++kh) {
        if (kh) __syncthreads();                  // protect Wt from prior readers
        // stage W[c][kh*64 + k] transposed into Wt[k][c]
#pragma unroll
        for (int p = 0; p < 8; ++p) {
            int c = c_lo + 16 * p;
            float4 w = *(const float4*)(W + (size_t)c * N_C + kh * 64 + k4);
            Wt[k4 + 0][c] = w.x;
            Wt[k4 + 1][c] = w.y;
            Wt[k4 + 2][c] = w.z;
            Wt[k4 + 3][c] = w.w;
        }
        __syncthreads();
#pragma unroll 4
        for (int k = 0; k < 64; ++k) {
            const float a0 = xs[r0c][kh * 64 + k];
            const float a1 = xs[r0c + 1][kh * 64 + k];
            const float4 b0 = *(const float4*)&Wt[k][c0];
            const float4 b1 = *(const float4*)&Wt[k][c0 + 4];
            acc[0][0] = fmaf(a0, b0.x, acc[0][0]);
            acc[0][1] = fmaf(a0, b0.y, acc[0][1]);
            acc[0][2] = fmaf(a0, b0.z, acc[0][2]);
            acc[0][3] = fmaf(a0, b0.w, acc[0][3]);
            acc[0][4] = fmaf(a0, b1.x, acc[0][4]);
            acc[0][5] = fmaf(a0, b1.y, acc[0][5]);
            acc[0][6] = fmaf(a0, b1.z, acc[0][6]);
            acc[0][7] = fmaf(a0, b1.w, acc[0][7]);
            acc[1][0] = fmaf(a1, b0.x, acc[1][0]);
            acc[1][1] = fmaf(a1, b0.y, acc[1][1]);
            acc[1][2] = fmaf(a1, b0.z, acc[1][2]);
            acc[1][3] = fmaf(a1, b0.w, acc[1][3]);
            acc[1][4] = fmaf(a1, b1.x, acc[1][4]);
            acc[1][5] = fmaf(a1, b1.y, acc[1][5]);
            acc[1][6] = fmaf(a1, b1.z, acc[1][6]);
            acc[1][7] = fmaf(a1, b1.w, acc[1][7]);
        }
    }
#pragma unroll
    for (int ri = 0; ri < 2; ++ri) {
        const int j = j0 + r0c + ri;
        const float d = dinv[j];
        float4 o0 = {d * acc[ri][0], d * acc[ri][1], d * acc[ri][2], d * acc[ri][3]};
        float4 o1 = {d * acc[ri][4], d * acc[ri][5], d * acc[ri][6], d * acc[ri][7]};
        *(float4*)(t + (size_t)j * N_C + c0)     = o0;
        *(float4*)(t + (size_t)j * N_C + c0 + 4) = o1;
    }
}

// ---------------------------------------------------------------------------
// Kernel C: (adj + I) @ t over a K-range.  BM=64 x BN=128 tile, 512 threads
// (8 waves/CU), per-thread 4x4, adj staged transposed for b128 frag reads.
// FUSE=true: single K-range, epilogue in-kernel.  FUSE=false: write partials.
// ---------------------------------------------------------------------------
template <bool FUSE>
__global__ __launch_bounds__(512) void k_spmm(const float* __restrict__ adj,
                                              const float* __restrict__ t,
                                              const float* __restrict__ dinv,
                                              const float* __restrict__ bias,
                                              float* __restrict__ outp,
                                              int klen) {
    __shared__ __align__(16) float aT[BK][BM + 4];   // [k][i], stride 68 (272B: b128-aligned)
    __shared__ __align__(16) float ts[BK][N_C];      // [k][c]
    const int tid   = threadIdx.x;
    const int i0    = blockIdx.x * BM;
    const int kbase = blockIdx.y * klen;
    const int nchunk = klen / BK;

    const int a_row = tid >> 4;              // 0..31 (+32 on 2nd pass)
    const int a_c4  = (tid & 15) * 4;        // k-offset in tile
    const int t_r   = tid >> 5;              // 0..15 (4 passes of +16)
    const int t_c4  = (tid & 31) * 4;

    float4 a_reg[2], t_reg[4];

    auto load_chunk = [&](int k0) {
#pragma unroll
        for (int p = 0; p < 2; ++p) {
            const int gi = i0 + a_row + p * 32;
            const int gj = k0 + a_c4;
            float4 v = *(const float4*)(adj + (size_t)gi * N_ROWS + gj);
            if (gi == gj)     v.x += 1.f;    // fold +I at stage time
            if (gi == gj + 1) v.y += 1.f;
            if (gi == gj + 2) v.z += 1.f;
            if (gi == gj + 3) v.w += 1.f;
            a_reg[p] = v;
        }
#pragma unroll
        for (int p = 0; p < 4; ++p)
            t_reg[p] = *(const float4*)(t + (size_t)(k0 + t_r + p * 16) * N_C + t_c4);
    };
    auto store_chunk = [&]() {
#pragma unroll
        for (int p = 0; p < 2; ++p) {
            const int r = a_row + p * 32;
            aT[a_c4 + 0][r] = a_reg[p].x;    // transposed scalar writes (amortized over 64 kk)
            aT[a_c4 + 1][r] = a_reg[p].y;
            aT[a_c4 + 2][r] = a_reg[p].z;
            aT[a_c4 + 3][r] = a_reg[p].w;
        }
#pragma unroll
        for (int p = 0; p < 4; ++p)
            *(float4*)&ts[t_r + p * 16][t_c4] = t_reg[p];
    };

    const int ctc = tid & 31, ctr = tid >> 5;     // 32 x 16 thread grid
    const int c0c = ctc * 4, r0c = ctr * 4;
    float acc[4][4];
#pragma unroll
    for (int i = 0; i < 4; ++i)
#pragma unroll
        for (int j = 0; j < 4; ++j) acc[i][j] = 0.f;

    load_chunk(kbase);
    store_chunk();
    __syncthreads();
    for (int ch = 0; ch < nchunk; ++ch) {
        const bool more = (ch + 1 < nchunk);
        if (more) load_chunk(kbase + (ch + 1) * BK);   // register prefetch hides HBM latency
#pragma unroll 4
        for (int kk = 0; kk < BK; ++kk) {
            const float4 av = *(const float4*)&aT[kk][r0c];   // broadcast b128
            const float4 bv = *(const float4*)&ts[kk][c0c];   // row-distinct b128
            acc[0][0] = fmaf(av.x, bv.x, acc[0][0]);
            acc[0][1] = fmaf(av.x, bv.y, acc[0][1]);
            acc[0][2] = fmaf(av.x, bv.z, acc[0][2]);
            acc[0][3] = fmaf(av.x, bv.w, acc[0][3]);
            acc[1][0] = fmaf(av.y, bv.x, acc[1][0]);
            acc[1][1] = fmaf(av.y, bv.y, acc[1][1]);
            acc[1][2] = fmaf(av.y, bv.z, acc[1][2]);
            acc[1][3] = fmaf(av.y, bv.w, acc[1][3]);
            acc[2][0] = fmaf(av.z, bv.x, acc[2][0]);
            acc[2][1] = fmaf(av.z, bv.y, acc[2][1]);
            acc[2][2] = fmaf(av.z, bv.z, acc[2][2]);
            acc[2][3] = fmaf(av.z, bv.w, acc[2][3]);
            acc[3][0] = fmaf(av.w, bv.x, acc[3][0]);
            acc[3][1] = fmaf(av.w, bv.y, acc[3][1]);
            acc[3][2] = fmaf(av.w, bv.z, acc[3][2]);
            acc[3][3] = fmaf(av.w, bv.w, acc[3][3]);
        }
        __syncthreads();                 // compute done before LDS overwrite
        if (more) {
            store_chunk();
            __syncthreads();             // LDS ready before next compute
        }
    }

#pragma unroll
    for (int ri = 0; ri < 4; ++ri) {
        const int gi = i0 + r0c + ri;
        float4 o = {acc[ri][0], acc[ri][1], acc[ri][2], acc[ri][3]};
        if (FUSE) {
            const float d = dinv[gi];
            const float4 bv = *(const float4*)(bias + c0c);
            o.x = d * o.x + bv.x;
            o.y = d * o.y + bv.y;
            o.z = d * o.z + bv.z;
            o.w = d * o.w + bv.w;
            *(float4*)(outp + (size_t)gi * N_C + c0c) = o;
        } else {
            float* p = outp + (size_t)blockIdx.y * ((size_t)N_ROWS * N_C);
            *(float4*)(p + (size_t)gi * N_C + c0c) = o;
        }
    }
}

// ---------------------------------------------------------------------------
// Kernel D: combine K-split partials + dinv row scale + bias.
// ---------------------------------------------------------------------------
__global__ __launch_bounds__(256) void k_combine(const float* __restrict__ part,
                                                 const float* __restrict__ dinv,
                                                 const float* __restrict__ bias,
                                                 float* __restrict__ outp) {
    const size_t gid = (size_t)blockIdx.x * 256 + threadIdx.x;
    const size_t off = gid * 4;
    const int i = (int)(off >> 7);
    const int c = (int)(off & 127);
    const float4 p0 = *(const float4*)(part + off);
    const float4 p1 = *(const float4*)(part + (size_t)N_ROWS * N_C + off);
    const float d = dinv[i];
    const float4 bv = *(const float4*)(bias + c);
    float4 o = {d * (p0.x + p1.x) + bv.x, d * (p0.y + p1.y) + bv.y,
                d * (p0.z + p1.z) + bv.z, d * (p0.w + p1.w) + bv.w};
    *(float4*)(outp + off) = o;
}

extern "C" void kernel_launch(void* const* d_in, const int* in_sizes, int n_in,
                              void* d_out, int out_size, void* d_ws, size_t ws_size,
                              hipStream_t stream) {
    const float* x   = (const float*)d_in[0];
    const float* adj = (const float*)d_in[1];
    const float* W   = (const float*)d_in[2];
    const float* b   = (const float*)d_in[3];
    float* out = (float*)d_out;

    float* dinv = (float*)d_ws;                              // 8192 floats
    float* t    = dinv + N_ROWS;                             // 1 Mi floats (4 MiB)
    float* part = t + (size_t)N_ROWS * N_C;                  // 2 x 1 Mi floats (8 MiB)
    const size_t need = ((size_t)N_ROWS + 3u * N_ROWS * N_C) * sizeof(float);
    const bool split = ws_size >= need;                      // ws_size constant -> same work every call

    k_rowsum<<<N_ROWS, 256, 0, stream>>>(adj, dinv);
    k_xw<<<N_ROWS / 32, 256, 0, stream>>>(x, W, dinv, t);
    if (split) {
        dim3 grid(N_ROWS / BM, 2);                           // K-split=2 -> 256 blocks, 8 waves/CU
        k_spmm<false><<<grid, 512, 0, stream>>>(adj, t, dinv, b, part, N_ROWS / 2);
        k_combine<<<(N_ROWS * N_C) / 1024, 256, 0, stream>>>(part, dinv, b, out);
    } else {
        dim3 grid(N_ROWS / BM, 1);
        k_spmm<true><<<grid, 512, 0, stream>>>(adj, t, dinv, b, out, N_ROWS);
    }
}

// Round 2
// 475.536 us; speedup vs baseline: 1.5931x; 1.5931x over previous
//
#include <hip/hip_runtime.h>

// SimpleGCNConv, N=8192, C=128, fp32 in/out.
//   out[i] = dinv[i] * ( (adj @ t)[i] + t[i] ) + b,   t[j] = dinv[j]*(x W^T)[j]
//   dinv = (1 + rowsum(adj))^-1/2
// adj@t runs on MFMA via bf16 emulation: adj = a_hi + a_lo (2x bf16), t -> bf16.
// Added error ~1e-5 absolute (<< current 4.9e-4 passing absmax).

#define N_ROWS 8192
#define N_C    128
#define NM     (8192 * 128)

typedef __bf16 bf16x8 __attribute__((ext_vector_type(8)));
typedef float  f32x4  __attribute__((ext_vector_type(4)));

// ---------------------------------------------------------------------------
// Kernel A: dinv[i] = (1 + rowsum(adj[i]))^-1/2.  One block per row.
// ---------------------------------------------------------------------------
__global__ __launch_bounds__(256) void k_rowsum(const float* __restrict__ adj,
                                                float* __restrict__ dinv) {
    const int row = blockIdx.x;
    const float4* rp = (const float4*)(adj + (size_t)row * N_ROWS);
    float s = 0.f;
#pragma unroll
    for (int i = 0; i < 8; ++i) {
        float4 v = rp[threadIdx.x + i * 256];
        s += (v.x + v.y) + (v.z + v.w);
    }
#pragma unroll
    for (int off = 32; off > 0; off >>= 1) s += __shfl_down(s, off, 64);
    __shared__ float red[4];
    const int lane = threadIdx.x & 63, wid = threadIdx.x >> 6;
    if (lane == 0) red[wid] = s;
    __syncthreads();
    if (threadIdx.x == 0) {
        float deg = 1.0f + ((red[0] + red[1]) + (red[2] + red[3]));
        dinv[row] = 1.0f / sqrtf(deg);
    }
}

// ---------------------------------------------------------------------------
// Kernel B: t = dinv .* (x @ W^T).  Writes t_nat fp32 [j][c] (for diagonal +
// combine) and tTh bf16 TRANSPOSED [c][j] (B-operand for the MFMA kernel).
// ---------------------------------------------------------------------------
__global__ __launch_bounds__(256) void k_xw(const float* __restrict__ x,
                                            const float* __restrict__ W,
                                            const float* __restrict__ dinv,
                                            float* __restrict__ tnat,
                                            __bf16* __restrict__ tTh) {
    __shared__ __align__(16) float WtBuf[64 * 132];   // [k][c] stride 132; reused as tt
    __shared__ __align__(16) float xs[32][128];
    const int tid = threadIdx.x;
    const int j0 = blockIdx.x * 32;

    {   // stage x tile
        const int c4 = (tid & 31) * 4;
        const int r0 = tid >> 5;
#pragma unroll
        for (int p = 0; p < 4; ++p)
            *(float4*)&xs[r0 + p * 8][c4] =
                *(const float4*)(x + (size_t)(j0 + r0 + p * 8) * N_C + c4);
    }

    const int tc = tid & 15, tr = tid >> 4;
    const int c0 = tc * 8, r0c = tr * 2;
    float acc[2][8];
#pragma unroll
    for (int i = 0; i < 2; ++i)
#pragma unroll
        for (int j = 0; j < 8; ++j) acc[i][j] = 0.f;

    const int c_lo = (tid & 7) + ((tid >> 7) << 3);
    const int k4   = ((tid >> 3) & 15) * 4;

    for (int kh = 0; kh < 2; ++kh) {
        if (kh) __syncthreads();
#pragma unroll
        for (int p = 0; p < 8; ++p) {
            int c = c_lo + 16 * p;
            float4 w = *(const float4*)(W + (size_t)c * N_C + kh * 64 + k4);
            WtBuf[(k4 + 0) * 132 + c] = w.x;
            WtBuf[(k4 + 1) * 132 + c] = w.y;
            WtBuf[(k4 + 2) * 132 + c] = w.z;
            WtBuf[(k4 + 3) * 132 + c] = w.w;
        }
        __syncthreads();
#pragma unroll 4
        for (int k = 0; k < 64; ++k) {
            const float a0 = xs[r0c][kh * 64 + k];
            const float a1 = xs[r0c + 1][kh * 64 + k];
            const float* wr = &WtBuf[k * 132 + c0];
            const float4 b0 = *(const float4*)wr;
            const float4 b1 = *(const float4*)(wr + 4);
#pragma unroll
            for (int q = 0; q < 4; ++q) {
                acc[0][q]     = fmaf(a0, ((const float*)&b0)[q], acc[0][q]);
                acc[0][q + 4] = fmaf(a0, ((const float*)&b1)[q], acc[0][q + 4]);
                acc[1][q]     = fmaf(a1, ((const float*)&b0)[q], acc[1][q]);
                acc[1][q + 4] = fmaf(a1, ((const float*)&b1)[q], acc[1][q + 4]);
            }
        }
    }

    __syncthreads();                         // all Wt reads done; reuse as tt[32][129]
    float* tt = WtBuf;
#pragma unroll
    for (int ri = 0; ri < 2; ++ri) {
        const int j = j0 + r0c + ri;
        const float d = dinv[j];
        float4 o0 = {d * acc[ri][0], d * acc[ri][1], d * acc[ri][2], d * acc[ri][3]};
        float4 o1 = {d * acc[ri][4], d * acc[ri][5], d * acc[ri][6], d * acc[ri][7]};
        *(float4*)(tnat + (size_t)j * N_C + c0)     = o0;
        *(float4*)(tnat + (size_t)j * N_C + c0 + 4) = o1;
#pragma unroll
        for (int q = 0; q < 4; ++q) {
            tt[(r0c + ri) * 129 + c0 + q]     = ((const float*)&o0)[q];
            tt[(r0c + ri) * 129 + c0 + 4 + q] = ((const float*)&o1)[q];
        }
    }
    __syncthreads();
    {   // transpose-out: thread -> 16 j's of one c, as bf16
        const int c  = tid >> 1;
        const int jh = (tid & 1) * 16;
        __bf16 ov[16];
#pragma unroll
        for (int q = 0; q < 16; ++q) ov[q] = (__bf16)tt[(jh + q) * 129 + c];
        __bf16* dst = tTh + (size_t)c * N_ROWS + j0 + jh;
        *(int4*)dst = ((const int4*)ov)[0];
        *(int4*)(dst + 8) = ((const int4*)ov)[1];
    }
}

// ---------------------------------------------------------------------------
// Kernel C: acc = adj @ t via MFMA bf16 (A = hi+lo split, B = t_hi).
// BM=128 x BN=128, 512 threads (8 waves, wave tile 32x64), BK=64 chunks with
// register prefetch.  FUSE: full epilogue; else raw fp32 partial per K-range.
// ---------------------------------------------------------------------------
template <bool FUSE>
__global__ __launch_bounds__(512) void k_spmm(const float* __restrict__ adj,
                                              const __bf16* __restrict__ tTh,
                                              const float* __restrict__ tnat,
                                              const float* __restrict__ dinv,
                                              const float* __restrict__ bias,
                                              float* __restrict__ outp,
                                              int klen) {
    __shared__ __align__(16) __bf16 Ah[128 * 72];   // [m][k], stride 72 (even bank spread)
    __shared__ __align__(16) __bf16 Al[128 * 72];
    __shared__ __align__(16) __bf16 Th[128 * 72];   // [n][k]
    const int tid   = threadIdx.x;
    const int i0    = blockIdx.x * 128;
    const int kbase = blockIdx.y * klen;
    const int nch   = klen / 64;

    float4 areg[2][2];
    int4   treg[2];

    auto load_chunk = [&](int k0) {
#pragma unroll
        for (int p = 0; p < 2; ++p) {
            const int s = tid + p * 512;
            const int r = s >> 3, kg = s & 7;
            const float* g = adj + (size_t)(i0 + r) * N_ROWS + k0 + kg * 8;
            areg[p][0] = *(const float4*)g;
            areg[p][1] = *(const float4*)(g + 4);
        }
        {
            const int n = tid >> 2, q = tid & 3;
            const int4* g = (const int4*)(tTh + (size_t)n * N_ROWS + k0 + q * 16);
            treg[0] = g[0];
            treg[1] = g[1];
        }
    };
    auto store_chunk = [&]() {
#pragma unroll
        for (int p = 0; p < 2; ++p) {
            const int s = tid + p * 512;
            const int r = s >> 3, kg = s & 7;
            __bf16 h[8], lo[8];
            const float* v = (const float*)&areg[p][0];
#pragma unroll
            for (int j = 0; j < 8; ++j) {
                h[j]  = (__bf16)v[j];
                lo[j] = (__bf16)(v[j] - (float)h[j]);
            }
            *(bf16x8*)&Ah[r * 72 + kg * 8] = *(const bf16x8*)h;
            *(bf16x8*)&Al[r * 72 + kg * 8] = *(const bf16x8*)lo;
        }
        {
            const int n = tid >> 2, q = tid & 3;
            *(int4*)&Th[n * 72 + q * 16]     = treg[0];
            *(int4*)&Th[n * 72 + q * 16 + 8] = treg[1];
        }
    };

    const int wv = tid >> 6, l = tid & 63;
    const int wm = wv >> 1, wn = wv & 1;
    const int lm = l & 15, lq = l >> 4;

    f32x4 acc[2][4] = {};

    load_chunk(kbase);
    store_chunk();
    __syncthreads();
    for (int ch = 0; ch < nch; ++ch) {
        const bool more = (ch + 1 < nch);
        if (more) load_chunk(kbase + (ch + 1) * 64);
#pragma unroll
        for (int ks = 0; ks < 2; ++ks) {
            const int ko = ks * 32 + lq * 8;
            bf16x8 a0h = *(const bf16x8*)&Ah[(wm * 32 + lm) * 72 + ko];
            bf16x8 a1h = *(const bf16x8*)&Ah[(wm * 32 + 16 + lm) * 72 + ko];
            bf16x8 a0l = *(const bf16x8*)&Al[(wm * 32 + lm) * 72 + ko];
            bf16x8 a1l = *(const bf16x8*)&Al[(wm * 32 + 16 + lm) * 72 + ko];
#pragma unroll
            for (int nt = 0; nt < 4; ++nt) {
                bf16x8 b = *(const bf16x8*)&Th[(wn * 64 + nt * 16 + lm) * 72 + ko];
                acc[0][nt] = __builtin_amdgcn_mfma_f32_16x16x32_bf16(a0h, b, acc[0][nt], 0, 0, 0);
                acc[1][nt] = __builtin_amdgcn_mfma_f32_16x16x32_bf16(a1h, b, acc[1][nt], 0, 0, 0);
                acc[0][nt] = __builtin_amdgcn_mfma_f32_16x16x32_bf16(a0l, b, acc[0][nt], 0, 0, 0);
                acc[1][nt] = __builtin_amdgcn_mfma_f32_16x16x32_bf16(a1l, b, acc[1][nt], 0, 0, 0);
            }
        }
        __syncthreads();
        if (more) {
            store_chunk();
            __syncthreads();
        }
    }

    // Epilogue.  D frag: col = lane&15, row = (lane>>4)*4 + reg  (m89)
    float* po = FUSE ? outp : outp + (size_t)blockIdx.y * NM;
#pragma unroll
    for (int mt = 0; mt < 2; ++mt)
#pragma unroll
        for (int nt = 0; nt < 4; ++nt) {
            const int col = wn * 64 + nt * 16 + lm;
#pragma unroll
            for (int r = 0; r < 4; ++r) {
                const int row = i0 + wm * 32 + mt * 16 + lq * 4 + r;
                float v = acc[mt][nt][r];
                if (FUSE)
                    v = dinv[row] * (v + tnat[(size_t)row * N_C + col]) + bias[col];
                po[(size_t)row * N_C + col] = v;
            }
        }
}

// ---------------------------------------------------------------------------
// Kernel D: out = dinv[i]*(sum_s part_s + t_nat) + b.
// ---------------------------------------------------------------------------
__global__ __launch_bounds__(256) void k_combine(const float* __restrict__ part,
                                                 const float* __restrict__ tnat,
                                                 const float* __restrict__ dinv,
                                                 const float* __restrict__ bias,
                                                 float* __restrict__ outp, int S) {
    const size_t off = ((size_t)blockIdx.x * 256 + threadIdx.x) * 4;
    const int i = (int)(off >> 7);
    const int c = (int)(off & 127);
    float4 s = *(const float4*)(tnat + off);
    for (int p = 0; p < S; ++p) {
        const float4 v = *(const float4*)(part + (size_t)p * NM + off);
        s.x += v.x; s.y += v.y; s.z += v.z; s.w += v.w;
    }
    const float d = dinv[i];
    const float4 bv = *(const float4*)(bias + c);
    float4 o = {d * s.x + bv.x, d * s.y + bv.y, d * s.z + bv.z, d * s.w + bv.w};
    *(float4*)(outp + off) = o;
}

extern "C" void kernel_launch(void* const* d_in, const int* in_sizes, int n_in,
                              void* d_out, int out_size, void* d_ws, size_t ws_size,
                              hipStream_t stream) {
    const float* x   = (const float*)d_in[0];
    const float* adj = (const float*)d_in[1];
    const float* W   = (const float*)d_in[2];
    const float* b   = (const float*)d_in[3];
    float* out = (float*)d_out;

    char* base = (char*)d_ws;
    float*  dinv = (float*)base;                                   // 32 KB
    float*  tnat = (float*)(base + 32768);                         // 4 MiB
    __bf16* tTh  = (__bf16*)(base + 32768 + (4u << 20));           // 2 MiB
    float*  part = (float*)(base + 32768 + (6u << 20));            // S x 4 MiB

    const size_t fixed = 32768 + (6u << 20);
    int S = 0;
    if (ws_size >= fixed + 4 * ((size_t)NM * 4)) S = 4;
    else if (ws_size >= fixed + 2 * ((size_t)NM * 4)) S = 2;

    k_rowsum<<<N_ROWS, 256, 0, stream>>>(adj, dinv);
    k_xw<<<N_ROWS / 32, 256, 0, stream>>>(x, W, dinv, tnat, tTh);
    if (S > 0) {
        dim3 grid(N_ROWS / 128, S);
        k_spmm<false><<<grid, 512, 0, stream>>>(adj, tTh, tnat, dinv, b, part, N_ROWS / S);
        k_combine<<<NM / 1024, 256, 0, stream>>>(part, tnat, dinv, b, out, S);
    } else {
        dim3 grid(N_ROWS / 128, 1);
        k_spmm<true><<<grid, 512, 0, stream>>>(adj, tTh, tnat, dinv, b, out, N_ROWS);
    }
}

// Round 3
// 460.131 us; speedup vs baseline: 1.6465x; 1.0335x over previous
//
#include <hip/hip_runtime.h>

// SimpleGCNConv, N=8192, C=128, fp32 in/out.
//   out[i] = dinv[i] * ( (adj @ t)[i] + t[i] ) + b,   t[j] = dinv[j]*(x W^T)[j]
//   dinv = (1 + rowsum(adj))^-1/2
// adj@t runs on MFMA via bf16 emulation: adj = a_hi + a_lo (2x bf16), t -> bf16.
// R3: K-split 4 -> 8 (512 blocks, 2 blocks/CU) so a second resident block
// covers the vmcnt(0) barrier drain. LDS 55KB/block -> exactly 2 fit.

#define N_ROWS 8192
#define N_C    128
#define NM     (8192 * 128)

typedef __bf16 bf16x8 __attribute__((ext_vector_type(8)));
typedef float  f32x4  __attribute__((ext_vector_type(4)));

// ---------------------------------------------------------------------------
// Kernel A: dinv[i] = (1 + rowsum(adj[i]))^-1/2.  One block per row.
// ---------------------------------------------------------------------------
__global__ __launch_bounds__(256) void k_rowsum(const float* __restrict__ adj,
                                                float* __restrict__ dinv) {
    const int row = blockIdx.x;
    const float4* rp = (const float4*)(adj + (size_t)row * N_ROWS);
    float s = 0.f;
#pragma unroll
    for (int i = 0; i < 8; ++i) {
        float4 v = rp[threadIdx.x + i * 256];
        s += (v.x + v.y) + (v.z + v.w);
    }
#pragma unroll
    for (int off = 32; off > 0; off >>= 1) s += __shfl_down(s, off, 64);
    __shared__ float red[4];
    const int lane = threadIdx.x & 63, wid = threadIdx.x >> 6;
    if (lane == 0) red[wid] = s;
    __syncthreads();
    if (threadIdx.x == 0) {
        float deg = 1.0f + ((red[0] + red[1]) + (red[2] + red[3]));
        dinv[row] = 1.0f / sqrtf(deg);
    }
}

// ---------------------------------------------------------------------------
// Kernel B: t = dinv .* (x @ W^T).  Writes t_nat fp32 [j][c] (for diagonal +
// combine) and tTh bf16 TRANSPOSED [c][j] (B-operand for the MFMA kernel).
// ---------------------------------------------------------------------------
__global__ __launch_bounds__(256) void k_xw(const float* __restrict__ x,
                                            const float* __restrict__ W,
                                            const float* __restrict__ dinv,
                                            float* __restrict__ tnat,
                                            __bf16* __restrict__ tTh) {
    __shared__ __align__(16) float WtBuf[64 * 132];   // [k][c] stride 132; reused as tt
    __shared__ __align__(16) float xs[32][128];
    const int tid = threadIdx.x;
    const int j0 = blockIdx.x * 32;

    {   // stage x tile
        const int c4 = (tid & 31) * 4;
        const int r0 = tid >> 5;
#pragma unroll
        for (int p = 0; p < 4; ++p)
            *(float4*)&xs[r0 + p * 8][c4] =
                *(const float4*)(x + (size_t)(j0 + r0 + p * 8) * N_C + c4);
    }

    const int tc = tid & 15, tr = tid >> 4;
    const int c0 = tc * 8, r0c = tr * 2;
    float acc[2][8];
#pragma unroll
    for (int i = 0; i < 2; ++i)
#pragma unroll
        for (int j = 0; j < 8; ++j) acc[i][j] = 0.f;

    const int c_lo = (tid & 7) + ((tid >> 7) << 3);
    const int k4   = ((tid >> 3) & 15) * 4;

    for (int kh = 0; kh < 2; ++kh) {
        if (kh) __syncthreads();
#pragma unroll
        for (int p = 0; p < 8; ++p) {
            int c = c_lo + 16 * p;
            float4 w = *(const float4*)(W + (size_t)c * N_C + kh * 64 + k4);
            WtBuf[(k4 + 0) * 132 + c] = w.x;
            WtBuf[(k4 + 1) * 132 + c] = w.y;
            WtBuf[(k4 + 2) * 132 + c] = w.z;
            WtBuf[(k4 + 3) * 132 + c] = w.w;
        }
        __syncthreads();
#pragma unroll 4
        for (int k = 0; k < 64; ++k) {
            const float a0 = xs[r0c][kh * 64 + k];
            const float a1 = xs[r0c + 1][kh * 64 + k];
            const float* wr = &WtBuf[k * 132 + c0];
            const float4 b0 = *(const float4*)wr;
            const float4 b1 = *(const float4*)(wr + 4);
#pragma unroll
            for (int q = 0; q < 4; ++q) {
                acc[0][q]     = fmaf(a0, ((const float*)&b0)[q], acc[0][q]);
                acc[0][q + 4] = fmaf(a0, ((const float*)&b1)[q], acc[0][q + 4]);
                acc[1][q]     = fmaf(a1, ((const float*)&b0)[q], acc[1][q]);
                acc[1][q + 4] = fmaf(a1, ((const float*)&b1)[q], acc[1][q + 4]);
            }
        }
    }

    __syncthreads();                         // all Wt reads done; reuse as tt[32][129]
    float* tt = WtBuf;
#pragma unroll
    for (int ri = 0; ri < 2; ++ri) {
        const int j = j0 + r0c + ri;
        const float d = dinv[j];
        float4 o0 = {d * acc[ri][0], d * acc[ri][1], d * acc[ri][2], d * acc[ri][3]};
        float4 o1 = {d * acc[ri][4], d * acc[ri][5], d * acc[ri][6], d * acc[ri][7]};
        *(float4*)(tnat + (size_t)j * N_C + c0)     = o0;
        *(float4*)(tnat + (size_t)j * N_C + c0 + 4) = o1;
#pragma unroll
        for (int q = 0; q < 4; ++q) {
            tt[(r0c + ri) * 129 + c0 + q]     = ((const float*)&o0)[q];
            tt[(r0c + ri) * 129 + c0 + 4 + q] = ((const float*)&o1)[q];
        }
    }
    __syncthreads();
    {   // transpose-out: thread -> 16 j's of one c, as bf16
        const int c  = tid >> 1;
        const int jh = (tid & 1) * 16;
        __bf16 ov[16];
#pragma unroll
        for (int q = 0; q < 16; ++q) ov[q] = (__bf16)tt[(jh + q) * 129 + c];
        __bf16* dst = tTh + (size_t)c * N_ROWS + j0 + jh;
        *(int4*)dst = ((const int4*)ov)[0];
        *(int4*)(dst + 8) = ((const int4*)ov)[1];
    }
}

// ---------------------------------------------------------------------------
// Kernel C: acc = adj @ t via MFMA bf16 (A = hi+lo split, B = t_hi).
// BM=128 x BN=128, 512 threads (8 waves, wave tile 32x64), BK=64 chunks with
// register prefetch.  FUSE: full epilogue; else raw fp32 partial per K-range.
// ---------------------------------------------------------------------------
template <bool FUSE>
__global__ __launch_bounds__(512) void k_spmm(const float* __restrict__ adj,
                                              const __bf16* __restrict__ tTh,
                                              const float* __restrict__ tnat,
                                              const float* __restrict__ dinv,
                                              const float* __restrict__ bias,
                                              float* __restrict__ outp,
                                              int klen) {
    __shared__ __align__(16) __bf16 Ah[128 * 72];   // [m][k], stride 72 (even bank spread)
    __shared__ __align__(16) __bf16 Al[128 * 72];
    __shared__ __align__(16) __bf16 Th[128 * 72];   // [n][k]
    const int tid   = threadIdx.x;
    const int i0    = blockIdx.x * 128;
    const int kbase = blockIdx.y * klen;
    const int nch   = klen / 64;

    float4 areg[2][2];
    int4   treg[2];

    auto load_chunk = [&](int k0) {
#pragma unroll
        for (int p = 0; p < 2; ++p) {
            const int s = tid + p * 512;
            const int r = s >> 3, kg = s & 7;
            const float* g = adj + (size_t)(i0 + r) * N_ROWS + k0 + kg * 8;
            areg[p][0] = *(const float4*)g;
            areg[p][1] = *(const float4*)(g + 4);
        }
        {
            const int n = tid >> 2, q = tid & 3;
            const int4* g = (const int4*)(tTh + (size_t)n * N_ROWS + k0 + q * 16);
            treg[0] = g[0];
            treg[1] = g[1];
        }
    };
    auto store_chunk = [&]() {
#pragma unroll
        for (int p = 0; p < 2; ++p) {
            const int s = tid + p * 512;
            const int r = s >> 3, kg = s & 7;
            __bf16 h[8], lo[8];
            const float* v = (const float*)&areg[p][0];
#pragma unroll
            for (int j = 0; j < 8; ++j) {
                h[j]  = (__bf16)v[j];
                lo[j] = (__bf16)(v[j] - (float)h[j]);
            }
            *(bf16x8*)&Ah[r * 72 + kg * 8] = *(const bf16x8*)h;
            *(bf16x8*)&Al[r * 72 + kg * 8] = *(const bf16x8*)lo;
        }
        {
            const int n = tid >> 2, q = tid & 3;
            *(int4*)&Th[n * 72 + q * 16]     = treg[0];
            *(int4*)&Th[n * 72 + q * 16 + 8] = treg[1];
        }
    };

    const int wv = tid >> 6, l = tid & 63;
    const int wm = wv >> 1, wn = wv & 1;
    const int lm = l & 15, lq = l >> 4;

    f32x4 acc[2][4] = {};

    load_chunk(kbase);
    store_chunk();
    __syncthreads();
    for (int ch = 0; ch < nch; ++ch) {
        const bool more = (ch + 1 < nch);
        if (more) load_chunk(kbase + (ch + 1) * 64);
#pragma unroll
        for (int ks = 0; ks < 2; ++ks) {
            const int ko = ks * 32 + lq * 8;
            bf16x8 a0h = *(const bf16x8*)&Ah[(wm * 32 + lm) * 72 + ko];
            bf16x8 a1h = *(const bf16x8*)&Ah[(wm * 32 + 16 + lm) * 72 + ko];
            bf16x8 a0l = *(const bf16x8*)&Al[(wm * 32 + lm) * 72 + ko];
            bf16x8 a1l = *(const bf16x8*)&Al[(wm * 32 + 16 + lm) * 72 + ko];
#pragma unroll
            for (int nt = 0; nt < 4; ++nt) {
                bf16x8 b = *(const bf16x8*)&Th[(wn * 64 + nt * 16 + lm) * 72 + ko];
                acc[0][nt] = __builtin_amdgcn_mfma_f32_16x16x32_bf16(a0h, b, acc[0][nt], 0, 0, 0);
                acc[1][nt] = __builtin_amdgcn_mfma_f32_16x16x32_bf16(a1h, b, acc[1][nt], 0, 0, 0);
                acc[0][nt] = __builtin_amdgcn_mfma_f32_16x16x32_bf16(a0l, b, acc[0][nt], 0, 0, 0);
                acc[1][nt] = __builtin_amdgcn_mfma_f32_16x16x32_bf16(a1l, b, acc[1][nt], 0, 0, 0);
            }
        }
        __syncthreads();
        if (more) {
            store_chunk();
            __syncthreads();
        }
    }

    // Epilogue.  D frag: col = lane&15, row = (lane>>4)*4 + reg  (m89)
    float* po = FUSE ? outp : outp + (size_t)blockIdx.y * NM;
#pragma unroll
    for (int mt = 0; mt < 2; ++mt)
#pragma unroll
        for (int nt = 0; nt < 4; ++nt) {
            const int col = wn * 64 + nt * 16 + lm;
#pragma unroll
            for (int r = 0; r < 4; ++r) {
                const int row = i0 + wm * 32 + mt * 16 + lq * 4 + r;
                float v = acc[mt][nt][r];
                if (FUSE)
                    v = dinv[row] * (v + tnat[(size_t)row * N_C + col]) + bias[col];
                po[(size_t)row * N_C + col] = v;
            }
        }
}

// ---------------------------------------------------------------------------
// Kernel D: out = dinv[i]*(sum_s part_s + t_nat) + b.
// ---------------------------------------------------------------------------
__global__ __launch_bounds__(256) void k_combine(const float* __restrict__ part,
                                                 const float* __restrict__ tnat,
                                                 const float* __restrict__ dinv,
                                                 const float* __restrict__ bias,
                                                 float* __restrict__ outp, int S) {
    const size_t off = ((size_t)blockIdx.x * 256 + threadIdx.x) * 4;
    const int i = (int)(off >> 7);
    const int c = (int)(off & 127);
    float4 s = *(const float4*)(tnat + off);
    for (int p = 0; p < S; ++p) {
        const float4 v = *(const float4*)(part + (size_t)p * NM + off);
        s.x += v.x; s.y += v.y; s.z += v.z; s.w += v.w;
    }
    const float d = dinv[i];
    const float4 bv = *(const float4*)(bias + c);
    float4 o = {d * s.x + bv.x, d * s.y + bv.y, d * s.z + bv.z, d * s.w + bv.w};
    *(float4*)(outp + off) = o;
}

extern "C" void kernel_launch(void* const* d_in, const int* in_sizes, int n_in,
                              void* d_out, int out_size, void* d_ws, size_t ws_size,
                              hipStream_t stream) {
    const float* x   = (const float*)d_in[0];
    const float* adj = (const float*)d_in[1];
    const float* W   = (const float*)d_in[2];
    const float* b   = (const float*)d_in[3];
    float* out = (float*)d_out;

    char* base = (char*)d_ws;
    float*  dinv = (float*)base;                                   // 32 KB
    float*  tnat = (float*)(base + 32768);                         // 4 MiB
    __bf16* tTh  = (__bf16*)(base + 32768 + (4u << 20));           // 2 MiB
    float*  part = (float*)(base + 32768 + (6u << 20));            // S x 4 MiB

    const size_t fixed = 32768 + (6u << 20);
    int S = 0;
    if      (ws_size >= fixed + 8 * ((size_t)NM * 4)) S = 8;   // 512 blocks, 2/CU
    else if (ws_size >= fixed + 4 * ((size_t)NM * 4)) S = 4;
    else if (ws_size >= fixed + 2 * ((size_t)NM * 4)) S = 2;

    k_rowsum<<<N_ROWS, 256, 0, stream>>>(adj, dinv);
    k_xw<<<N_ROWS / 32, 256, 0, stream>>>(x, W, dinv, tnat, tTh);
    if (S > 0) {
        dim3 grid(N_ROWS / 128, S);
        k_spmm<false><<<grid, 512, 0, stream>>>(adj, tTh, tnat, dinv, b, part, N_ROWS / S);
        k_combine<<<NM / 1024, 256, 0, stream>>>(part, tnat, dinv, b, out, S);
    } else {
        dim3 grid(N_ROWS / 128, 1);
        k_spmm<true><<<grid, 512, 0, stream>>>(adj, tTh, tnat, dinv, b, out, N_ROWS);
    }
}